// Round 5
// baseline (6433.952 us; speedup 1.0000x reference)
//
#include <hip/hip_runtime.h>
#include <cstdint>
#include <cstddef>

#define NB 8
#define NT 4096
#define NI 128
#define NH 256
#define NH2 512
#define NO 64
#define NSLICE 8
#define NJS 32

// workspace float offsets
#define OFF_H64   0          // packed h (L2 fast-path): 16 teams * 2 parity * 256 u64
#define OFF_MIR   16384      // packed h mirror (IF$ agent path): same shape
#define OFF_XCC   32768      // team formation: 128 WGs * 1 u64 (=256 floats)
#define OFF_SC    33024      // scores: 8*4096 (softmax in-place -> also 'a')
#define OFF_CTX   65792      // ctx: 8*512
#define OFF_WT    69888      // w_att transposed: 512*512
#define OFF_PRED  332032     // pred: 8*4096*512
#define ZERO_FLOATS 69888    // zero h64 + mirror + xcc + scores + ctx

// ---- memory helpers --------------------------------------------------------
// st_plain: normal store -> vector L0 (write-through) -> shared per-XCD L2.
// ld_l2:    sc0 load (L0-bypass) -> reads the shared per-XCD L2.
__device__ __forceinline__ void st_plain(unsigned long long* p, unsigned long long v) {
    asm volatile("global_store_dwordx2 %0, %1, off" :: "v"(p), "v"(v) : "memory");
}
__device__ __forceinline__ unsigned long long ld_l2(const unsigned long long* p) {
    unsigned long long v;
    asm volatile("global_load_dwordx2 %0, %1, off sc0\n\ts_waitcnt vmcnt(0)"
                 : "=v"(v) : "v"(p) : "memory");
    return v;
}

// ---------------------------------------------------------------------------
// Persistent bidirectional GRU recurrence (round-2 protocol) with RUNTIME
// TEAM FORMATION: WG roles (dir,b,slice) are assigned from measured
// HW_REG_XCC_ID so that every 8-WG team is XCD-pure by construction
// (no placement assumptions). Within a pure team, h exchange uses the
// same-XCD L2: plain store publish + bounded sc0 poll; an always-written
// agent-scope mirror guarantees liveness (grace period prevents startup-skew
// sticky downgrades). Impure teams (pathological placement) use mirror only.
// ---------------------------------------------------------------------------
__global__ __launch_bounds__(384, 1) void gru_rec(
    const float* __restrict__ x,
    const float* __restrict__ w_ih_f, const float* __restrict__ w_hh_f,
    const float* __restrict__ b_ih_f, const float* __restrict__ b_hh_f,
    const float* __restrict__ w_ih_b, const float* __restrict__ w_hh_b,
    const float* __restrict__ b_ih_b, const float* __restrict__ b_hh_b,
    unsigned long long* __restrict__ hbuf, unsigned long long* __restrict__ mir,
    unsigned long long* __restrict__ xccbuf, float* __restrict__ pred)
{
    const int wg = blockIdx.x;
    const int tid = threadIdx.x;
    const int row = tid >> 2;      // 0..95
    const int q = tid & 3;         // col quarter
    const int g = row >> 5;        // gate 0=r,1=z,2=n
    const int jj = row & 31;

    __shared__ float h_lds[268];   // index c + 4*(c>>6): quarters bank-disjoint
    __shared__ float x_lds[140];   // index c + 4*(c>>5)
    __shared__ float gx_l[96], gh_l[96];
    __shared__ unsigned short xcc_l[128];
    __shared__ int s_team, s_slice, s_fast;

    // ---- team formation: publish my XCD, all-gather, counting-sort ----
    if (tid == 0) {
        unsigned xcc;
        asm volatile("s_getreg_b32 %0, hwreg(HW_REG_XCC_ID)" : "=s"(xcc));
        xcc &= 0xFu;
        __hip_atomic_store(&xccbuf[wg], (1ull << 32) | (unsigned long long)xcc,
                           __ATOMIC_RELAXED, __HIP_MEMORY_SCOPE_AGENT);
    }
    if (tid < 128) {
        unsigned long long pk;
        do {
            pk = __hip_atomic_load(&xccbuf[tid], __ATOMIC_RELAXED,
                                   __HIP_MEMORY_SCOPE_AGENT);
        } while ((unsigned)(pk >> 32) != 1u);
        xcc_l[tid] = (unsigned short)(unsigned)pk;
    }
    __syncthreads();
    if (tid == 0) {
        int cnt[16];
        for (int b2 = 0; b2 < 16; ++b2) cnt[b2] = 0;
        for (int j = 0; j < 128; ++j) cnt[xcc_l[j]]++;
        int pref[17]; pref[0] = 0;
        for (int b2 = 0; b2 < 16; ++b2) pref[b2 + 1] = pref[b2] + cnt[b2];
        const int myx = xcc_l[wg];
        int within = 0;
        for (int j = 0; j < wg; ++j) within += (xcc_l[j] == myx);
        const int rank = pref[myx] + within;
        const int team = rank >> 3;
        const int lo = team * 8, hi = lo + 8;
        int pure = 0;
        for (int b2 = 0; b2 < 16; ++b2)
            if (pref[b2] <= lo && hi <= pref[b2 + 1]) pure = 1;
        s_team = team; s_slice = rank & 7; s_fast = pure;
    }
    __syncthreads();
    const int team = s_team;
    const int slice = s_slice;
    const int dir = team & 1;
    const int bb = team >> 1;
    bool use_fast = (s_fast != 0);

    const int grow = g * NH + slice * NJS + jj;
    const float* wih = dir ? w_ih_b : w_ih_f;
    const float* whh = dir ? w_hh_b : w_hh_f;
    const float* bih = dir ? b_ih_b : b_ih_f;
    const float* bhh = dir ? b_hh_b : b_hh_f;

    // one-time weight preload into registers
    float wh[64], wi[32];
    {
        const float* p = whh + (size_t)grow * NH + q * 64;
        #pragma unroll
        for (int i = 0; i < 16; ++i) {
            float4 v = *(const float4*)(p + i * 4);
            wh[4*i] = v.x; wh[4*i+1] = v.y; wh[4*i+2] = v.z; wh[4*i+3] = v.w;
        }
        const float* p2 = wih + (size_t)grow * NI + q * 32;
        #pragma unroll
        for (int i = 0; i < 8; ++i) {
            float4 v = *(const float4*)(p2 + i * 4);
            wi[4*i] = v.x; wi[4*i+1] = v.y; wi[4*i+2] = v.z; wi[4*i+3] = v.w;
        }
    }
    const float bi = bih[grow];
    const float bh = bhh[grow];

    unsigned long long* hb = hbuf + (size_t)team * 2 * NH;   // [parity][256]
    unsigned long long* mb = mir  + (size_t)team * 2 * NH;
    const float* xb = x + (size_t)bb * NT * NI;
    float* predb = pred + (size_t)bb * NT * NH2 + dir * NH;

    // prefetch x for step 0 into a register
    const int xc = tid - NH;        // 0..127 for tid>=256
    float xreg = 0.f;
    if (tid >= NH) {
        const int t0 = dir ? (NT - 1) : 0;
        xreg = xb[(size_t)t0 * NI + xc];
    }

    for (int s = 0; s < NT; ++s) {
        const int t = dir ? (NT - 1 - s) : s;
        const int pr = s & 1, pw = pr ^ 1;

        // P1: obtain h_{s} (tag==s) into LDS; stage prefetched x_t
        if (tid < NH) {
            const unsigned tag = (unsigned)s;
            unsigned long long pk = 0;
            bool got = false;
            if (use_fast) {
                const unsigned long long* fp = hb + pr * NH + tid;
                #pragma unroll 1
                for (int tries = 0; tries < 64; ++tries) {
                    pk = ld_l2(fp);
                    if ((unsigned)(pk >> 32) == tag) { got = true; break; }
                }
                // grace period: startup skew must not kill the fast path
                if (!got && s >= 16) use_fast = false;
            }
            if (!got) {
                const unsigned long long* mp = mb + pr * NH + tid;
                do {
                    pk = __hip_atomic_load(mp, __ATOMIC_RELAXED,
                                           __HIP_MEMORY_SCOPE_AGENT);
                } while ((unsigned)(pk >> 32) != tag);
            }
            h_lds[tid + 4 * (tid >> 6)] = __uint_as_float((unsigned)pk);
        } else {
            x_lds[xc + 4 * (xc >> 5)] = xreg;
        }
        __syncthreads();

        // P2: partial dots against register weights (multi-accumulator:
        // break the serial FMA dependency chain on the ring)
        float ah0 = 0.f, ah1 = 0.f, ah2 = 0.f, ah3 = 0.f;
        float ax0 = 0.f, ax1 = 0.f;
        {
            const float* hp = h_lds + q * 68;
            #pragma unroll
            for (int i = 0; i < 16; ++i) {
                ah0 += wh[i]      * hp[i];
                ah1 += wh[16 + i] * hp[16 + i];
                ah2 += wh[32 + i] * hp[32 + i];
                ah3 += wh[48 + i] * hp[48 + i];
            }
            const float* xp = x_lds + q * 36;
            #pragma unroll
            for (int i = 0; i < 16; ++i) {
                ax0 += wi[i]      * xp[i];
                ax1 += wi[16 + i] * xp[16 + i];
            }
        }
        float ah = (ah0 + ah1) + (ah2 + ah3);
        float ax = ax0 + ax1;
        ah += __shfl_xor(ah, 1); ah += __shfl_xor(ah, 2);
        ax += __shfl_xor(ax, 1); ax += __shfl_xor(ax, 2);
        if (q == 0) { gx_l[row] = ax + bi; gh_l[row] = ah + bh; }
        // prefetch next step's x (latency hides under P3 + next poll)
        if (tid >= NH && s + 1 < NT) {
            const int tn = dir ? (NT - 2 - s) : (s + 1);
            xreg = xb[(size_t)tn * NI + xc];
        }
        __syncthreads();

        // P3: gate combine on 32 lanes, publish h_{s+1}
        if (tid < NJS) {
            const float xr = gx_l[tid],      hr = gh_l[tid];
            const float xz = gx_l[32 + tid], hz = gh_l[32 + tid];
            const float xn = gx_l[64 + tid], hn = gh_l[64 + tid];
            const float r = 1.f / (1.f + __expf(-(xr + hr)));
            const float z = 1.f / (1.f + __expf(-(xz + hz)));
            const float y = xn + r * hn;
            const float e2 = __expf(-2.f * y);
            const float n = (1.f - e2) / (1.f + e2);
            const int c = slice * NJS + tid;
            const float hold = h_lds[c + 4 * (c >> 6)];
            const float hnew = (1.f - z) * n + z * hold;
            predb[(size_t)t * NH2 + c] = hnew;
            const unsigned long long pk =
                ((unsigned long long)(unsigned)(s + 1) << 32) |
                (unsigned long long)__float_as_uint(hnew);
            st_plain(hb + pw * NH + c, pk);                         // L2 fast path
            __hip_atomic_store(mb + pw * NH + c, pk,                // IF$ mirror
                               __ATOMIC_RELAXED, __HIP_MEMORY_SCOPE_AGENT);
        }
        __syncthreads();
    }
}

// ---------------------------------------------------------------------------
// w_att transpose: wT[k][h] = w_att[h][k]
// ---------------------------------------------------------------------------
__global__ void transpose_watt(const float* __restrict__ w_att, float* __restrict__ wT) {
    const int n = blockIdx.x * 256 + threadIdx.x;   // 0..262143
    const int k = n >> 9, h = n & 511;
    wT[n] = w_att[h * NH2 + k];
}

// ---------------------------------------------------------------------------
// Fused scores = sum_k tanh(pred @ w_att)[.,k] * v[k], tiled 64t x 64k,
// K(=h)=512 chunked by 64 through LDS. Partial scores via atomicAdd.
// ---------------------------------------------------------------------------
__global__ __launch_bounds__(256) void scores_gemm(
    const float* __restrict__ pred, const float* __restrict__ wT,
    const float* __restrict__ v_att, float* __restrict__ scores)
{
    const int tt = blockIdx.x, kt = blockIdx.y, bb = blockIdx.z;
    const int tid = threadIdx.x;
    const int tx = tid & 15;   // k micro index
    const int ty = tid >> 4;   // t micro index
    __shared__ float As[64][68];   // [t][h]
    __shared__ float Bs[64][68];   // [h][k]
    __shared__ float red[64][17];
    float acc[4][4] = {{0.f}};
    const int t0 = tt * 64, k0 = kt * 64;
    const float* pb = pred + ((size_t)bb * NT + t0) * NH2;

    for (int hc = 0; hc < NH2; hc += 64) {
        #pragma unroll
        for (int r = 0; r < 4; ++r) {
            const int idx = tid + 256 * r;
            const int tr = idx >> 4;           // row 0..63
            const int c4 = (idx & 15) * 4;     // col 0..60
            float4 a = *(const float4*)(pb + (size_t)tr * NH2 + hc + c4);
            *(float4*)&As[tr][c4] = a;
            float4 w = *(const float4*)(wT + (size_t)(k0 + tr) * NH2 + hc + c4);
            Bs[c4 + 0][tr] = w.x; Bs[c4 + 1][tr] = w.y;
            Bs[c4 + 2][tr] = w.z; Bs[c4 + 3][tr] = w.w;
        }
        __syncthreads();
        #pragma unroll
        for (int h = 0; h < 64; ++h) {
            const float a0 = As[ty*4+0][h], a1 = As[ty*4+1][h];
            const float a2 = As[ty*4+2][h], a3 = As[ty*4+3][h];
            const float4 bv = *(const float4*)&Bs[h][tx*4];
            acc[0][0] += a0*bv.x; acc[0][1] += a0*bv.y; acc[0][2] += a0*bv.z; acc[0][3] += a0*bv.w;
            acc[1][0] += a1*bv.x; acc[1][1] += a1*bv.y; acc[1][2] += a1*bv.z; acc[1][3] += a1*bv.w;
            acc[2][0] += a2*bv.x; acc[2][1] += a2*bv.y; acc[2][2] += a2*bv.z; acc[2][3] += a2*bv.w;
            acc[3][0] += a3*bv.x; acc[3][1] += a3*bv.y; acc[3][2] += a3*bv.z; acc[3][3] += a3*bv.w;
        }
        __syncthreads();
    }
    const float4 vv = *(const float4*)(v_att + k0 + tx * 4);
    #pragma unroll
    for (int i = 0; i < 4; ++i) {
        const float p = tanhf(acc[i][0]) * vv.x + tanhf(acc[i][1]) * vv.y
                      + tanhf(acc[i][2]) * vv.z + tanhf(acc[i][3]) * vv.w;
        red[ty*4+i][tx] = p;
    }
    __syncthreads();
    if (tid < 64) {
        float ssum = 0.f;
        #pragma unroll
        for (int xx = 0; xx < 16; ++xx) ssum += red[tid][xx];
        atomicAdd(&scores[bb * NT + t0 + tid], ssum);
    }
}

// ---------------------------------------------------------------------------
// softmax over T per batch (in-place)
// ---------------------------------------------------------------------------
__global__ void softmax_t(float* __restrict__ scores) {
    const int bb = blockIdx.x;
    const int tid = threadIdx.x;   // 256
    __shared__ float red[256];
    float m = -1e30f;
    for (int t = tid; t < NT; t += 256) m = fmaxf(m, scores[bb*NT + t]);
    red[tid] = m; __syncthreads();
    for (int s2 = 128; s2; s2 >>= 1) { if (tid < s2) red[tid] = fmaxf(red[tid], red[tid+s2]); __syncthreads(); }
    m = red[0]; __syncthreads();
    float sum = 0.f;
    for (int t = tid; t < NT; t += 256) sum += expf(scores[bb*NT + t] - m);
    red[tid] = sum; __syncthreads();
    for (int s2 = 128; s2; s2 >>= 1) { if (tid < s2) red[tid] += red[tid+s2]; __syncthreads(); }
    const float inv = 1.f / red[0];
    for (int t = tid; t < NT; t += 256) scores[bb*NT + t] = expf(scores[bb*NT + t] - m) * inv;
}

// ---------------------------------------------------------------------------
// ctx[b][h] = sum_t a[b][t] * pred[b][t][h]  (partial per t-chunk, atomicAdd)
// ---------------------------------------------------------------------------
__global__ void ctx_kernel(const float* __restrict__ pred, const float* __restrict__ a,
                           float* __restrict__ ctx) {
    const int bb = blockIdx.x, ch = blockIdx.y;   // 32 chunks of 128 t
    const int tid = threadIdx.x;                  // 256
    const int t0 = ch * 128;
    float acc0 = 0.f, acc1 = 0.f;
    for (int t = 0; t < 128; ++t) {
        const float av = a[bb*NT + t0 + t];
        const float* p = pred + ((size_t)bb * NT + t0 + t) * NH2;
        acc0 += av * p[tid];
        acc1 += av * p[tid + 256];
    }
    atomicAdd(&ctx[bb*NH2 + tid], acc0);
    atomicAdd(&ctx[bb*NH2 + tid + 256], acc1);
}

// ---------------------------------------------------------------------------
// logits = ctx @ w_lin^T + b_lin ; out = softmax(logits) per batch.
// ---------------------------------------------------------------------------
__global__ __launch_bounds__(512) void final_kernel(
    const float* __restrict__ ctx, const float* __restrict__ w_lin,
    const float* __restrict__ b_lin, float* __restrict__ out)
{
    const int tid = threadIdx.x;
    const int bb = tid >> 6, o = tid & 63;
    __shared__ float cl[NB][NH2];
    for (int i = tid; i < NB * NH2; i += 512) cl[i >> 9][i & 511] = ctx[i];
    __syncthreads();
    float acc = b_lin[o];
    for (int h = 0; h < NH2; h += 4) {
        const float4 w = *(const float4*)&w_lin[o * NH2 + h];
        acc += cl[bb][h]*w.x + cl[bb][h+1]*w.y + cl[bb][h+2]*w.z + cl[bb][h+3]*w.w;
    }
    float m = acc;
    for (int off = 32; off; off >>= 1) m = fmaxf(m, __shfl_xor(m, off));
    const float e = expf(acc - m);
    float ssum = e;
    for (int off = 32; off; off >>= 1) ssum += __shfl_xor(ssum, off);
    out[tid] = e / ssum;
}

extern "C" void kernel_launch(void* const* d_in, const int* in_sizes, int n_in,
                              void* d_out, int out_size, void* d_ws, size_t ws_size,
                              hipStream_t stream) {
    (void)in_sizes; (void)n_in; (void)out_size; (void)ws_size;
    const float* x      = (const float*)d_in[0];
    const float* w_ih_f = (const float*)d_in[1];
    const float* w_hh_f = (const float*)d_in[2];
    const float* b_ih_f = (const float*)d_in[3];
    const float* b_hh_f = (const float*)d_in[4];
    const float* w_ih_b = (const float*)d_in[5];
    const float* w_hh_b = (const float*)d_in[6];
    const float* b_ih_b = (const float*)d_in[7];
    const float* b_hh_b = (const float*)d_in[8];
    const float* w_att  = (const float*)d_in[9];
    const float* v_att  = (const float*)d_in[10];
    const float* w_lin  = (const float*)d_in[11];
    const float* b_lin  = (const float*)d_in[12];

    float* ws     = (float*)d_ws;
    unsigned long long* hbuf = (unsigned long long*)(ws + OFF_H64);
    unsigned long long* mir  = (unsigned long long*)(ws + OFF_MIR);
    unsigned long long* xcc  = (unsigned long long*)(ws + OFF_XCC);
    float* scores = ws + OFF_SC;     // softmax in-place -> also 'a'
    float* ctx    = ws + OFF_CTX;
    float* wT     = ws + OFF_WT;
    float* pred   = ws + OFF_PRED;
    float* out    = (float*)d_out;

    hipMemsetAsync(d_ws, 0, (size_t)ZERO_FLOATS * sizeof(float), stream);
    hipLaunchKernelGGL(transpose_watt, dim3(1024), dim3(256), 0, stream, w_att, wT);
    hipLaunchKernelGGL(gru_rec, dim3(128), dim3(384), 0, stream,
                       x, w_ih_f, w_hh_f, b_ih_f, b_hh_f,
                       w_ih_b, w_hh_b, b_ih_b, b_hh_b, hbuf, mir, xcc, pred);
    hipLaunchKernelGGL(scores_gemm, dim3(64, 8, 8), dim3(256), 0, stream,
                       pred, wT, v_att, scores);
    hipLaunchKernelGGL(softmax_t, dim3(8), dim3(256), 0, stream, scores);
    hipLaunchKernelGGL(ctx_kernel, dim3(8, 32), dim3(256), 0, stream, pred, scores, ctx);
    hipLaunchKernelGGL(final_kernel, dim3(1), dim3(512), 0, stream, ctx, w_lin, b_lin, out);
}

// Round 6
// 5236.143 us; speedup vs baseline: 1.2288x; 1.2288x over previous
//
#include <hip/hip_runtime.h>
#include <cstdint>
#include <cstddef>

#define NB 8
#define NT 4096
#define NI 128
#define NH 256
#define NH2 512
#define NO 64
#define NSLICE 8
#define NJS 32

// workspace float offsets
#define OFF_MIR   0          // packed h: 16 teams * 2 parity * 256 u64 = 16384 floats
#define OFF_SC    16384      // scores: 8*4096 (softmax in-place -> also 'a')
#define OFF_CTX   49152      // ctx: 8*512
#define OFF_WT    53248      // w_att transposed: 512*512
#define OFF_PRED  315392     // pred: 8*4096*512
#define ZERO_FLOATS 53248    // zero mirror + scores + ctx

// ---------------------------------------------------------------------------
// Persistent bidirectional GRU recurrence. Transport = round-2/4 proven
// protocol ONLY: one 64-bit word per h element = (step_tag<<32)|f32 bits,
// RELAXED agent-scope atomics, parity double-buffer. (R3/R5 established that
// same-XCD L2 "fast paths" do not beat this on gfx950 — do not reintroduce.)
//
// Structural change vs R4: 2 barriers/step with role-overlapped phase A.
//   A: lanes 0-31  : gates from g[s&1] (dbuf) -> h_{s+1}; PUBLISH FIRST-thing;
//                    pred store; own h_lds write (h_prev carried in register).
//      lanes 64-287: poll the 224 remote words (start immediately, overlapped
//                    with producers' gate tails in other WGs).
//      lanes 320-383: stage x_{t(s+1)} from regs; prefetch x_{t(s+2)}.
//   bar
//   B: all 384: dots (multi-accumulator) -> g[(s+1)&1]
//   bar
// grid = 128 WGs: wg = dir + 2*b + 16*slice (8 slices of 32 h-outputs).
// ---------------------------------------------------------------------------
__global__ __launch_bounds__(384, 1) void gru_rec(
    const float* __restrict__ x,
    const float* __restrict__ w_ih_f, const float* __restrict__ w_hh_f,
    const float* __restrict__ b_ih_f, const float* __restrict__ b_hh_f,
    const float* __restrict__ w_ih_b, const float* __restrict__ w_hh_b,
    const float* __restrict__ b_ih_b, const float* __restrict__ b_hh_b,
    unsigned long long* __restrict__ mir, float* __restrict__ pred)
{
    const int wg = blockIdx.x;
    const int dir = wg & 1;
    const int bb = (wg >> 1) & 7;
    const int slice = wg >> 4;
    const int tid = threadIdx.x;
    const int row = tid >> 2;      // 0..95
    const int q = tid & 3;         // col quarter
    const int g = row >> 5;        // gate 0=r,1=z,2=n
    const int jj = row & 31;
    const int grow = g * NH + slice * NJS + jj;

    const float* wih = dir ? w_ih_b : w_ih_f;
    const float* whh = dir ? w_hh_b : w_hh_f;
    const float* bih = dir ? b_ih_b : b_ih_f;
    const float* bhh = dir ? b_hh_b : b_hh_f;

    // one-time weight preload into registers
    float wh[64], wi[32];
    {
        const float* p = whh + (size_t)grow * NH + q * 64;
        #pragma unroll
        for (int i = 0; i < 16; ++i) {
            float4 v = *(const float4*)(p + i * 4);
            wh[4*i] = v.x; wh[4*i+1] = v.y; wh[4*i+2] = v.z; wh[4*i+3] = v.w;
        }
        const float* p2 = wih + (size_t)grow * NI + q * 32;
        #pragma unroll
        for (int i = 0; i < 8; ++i) {
            float4 v = *(const float4*)(p2 + i * 4);
            wi[4*i] = v.x; wi[4*i+1] = v.y; wi[4*i+2] = v.z; wi[4*i+3] = v.w;
        }
    }
    const float bi = bih[grow];
    const float bh = bhh[grow];

    __shared__ float h_lds[268];     // index c + 4*(c>>6): quarters bank-disjoint
    __shared__ float x_lds[140];     // index c + 4*(c>>5)
    __shared__ float gx_l[2][96], gh_l[2][96];   // parity double-buffered

    unsigned long long* mb = mir + (size_t)(dir * NB + bb) * 2 * NH;  // [parity][256]
    const float* xb = x + (size_t)bb * NT * NI;
    float* predb = pred + (size_t)bb * NT * NH2 + dir * NH;

    // ---- prologue: h_0 = 0; stage x_{t(0)}; prefetch x_{t(1)} ----
    if (tid < NH) h_lds[tid + 4 * (tid >> 6)] = 0.f;
    float hprev = 0.f;
    float xr0 = 0.f, xr1 = 0.f;
    if (tid >= 320) {
        const int i0 = tid - 320;                 // 0..63, two floats each
        const int t0 = dir ? (NT - 1) : 0;
        x_lds[i0 + 4 * (i0 >> 5)] = xb[(size_t)t0 * NI + i0];
        { const int c1 = i0 + 64; x_lds[c1 + 4 * (c1 >> 5)] = xb[(size_t)t0 * NI + c1]; }
        const int t1 = dir ? (NT - 2) : 1;
        xr0 = xb[(size_t)t1 * NI + i0];
        xr1 = xb[(size_t)t1 * NI + i0 + 64];
    }
    __syncthreads();

    // ---- D_0: dots over h_0 = 0 and x_{t(0)} -> g[0] ----
    {
        float ah0 = 0.f, ah1 = 0.f, ah2 = 0.f, ah3 = 0.f;
        float ax0 = 0.f, ax1 = 0.f;
        const float* hp = h_lds + q * 68;
        #pragma unroll
        for (int i = 0; i < 16; ++i) {
            ah0 += wh[i]      * hp[i];
            ah1 += wh[16 + i] * hp[16 + i];
            ah2 += wh[32 + i] * hp[32 + i];
            ah3 += wh[48 + i] * hp[48 + i];
        }
        const float* xp = x_lds + q * 36;
        #pragma unroll
        for (int i = 0; i < 16; ++i) {
            ax0 += wi[i]      * xp[i];
            ax1 += wi[16 + i] * xp[16 + i];
        }
        float ah = (ah0 + ah1) + (ah2 + ah3);
        float ax = ax0 + ax1;
        ah += __shfl_xor(ah, 1); ah += __shfl_xor(ah, 2);
        ax += __shfl_xor(ax, 1); ax += __shfl_xor(ax, 2);
        if (q == 0) { gx_l[0][row] = ax + bi; gh_l[0][row] = ah + bh; }
    }
    __syncthreads();

    for (int s = 0; s < NT; ++s) {
        const int t = dir ? (NT - 1 - s) : s;
        const int p = s & 1;
        const int pw = (s + 1) & 1;

        // ---- Phase A ----
        if (tid < NJS) {
            // gates -> h_{s+1}; publish as early as possible
            const float xr = gx_l[p][tid],      hr = gh_l[p][tid];
            const float xz = gx_l[p][32 + tid], hz = gh_l[p][32 + tid];
            const float xn = gx_l[p][64 + tid], hn = gh_l[p][64 + tid];
            const float r = 1.f / (1.f + __expf(-(xr + hr)));
            const float z = 1.f / (1.f + __expf(-(xz + hz)));
            const float y = xn + r * hn;
            const float e2 = __expf(-2.f * y);
            const float n = (1.f - e2) / (1.f + e2);
            const float hnew = (1.f - z) * n + z * hprev;
            const int c = slice * NJS + tid;
            const unsigned long long pk =
                ((unsigned long long)(unsigned)(s + 1) << 32) |
                (unsigned long long)__float_as_uint(hnew);
            __hip_atomic_store(mb + (size_t)pw * NH + c, pk,
                               __ATOMIC_RELAXED, __HIP_MEMORY_SCOPE_AGENT);
            predb[(size_t)t * NH2 + c] = hnew;
            h_lds[c + 4 * (c >> 6)] = hnew;
            hprev = hnew;
        } else if (tid >= 64 && tid < 288) {
            // poll one remote word (starts immediately at phase entry)
            const int idx = tid - 64;                       // 0..223
            const int rc = idx < slice * NJS ? idx : idx + NJS;
            const unsigned long long* ap = mb + (size_t)pw * NH + rc;
            const unsigned tag = (unsigned)(s + 1);
            unsigned long long pk;
            do {
                pk = __hip_atomic_load(ap, __ATOMIC_RELAXED,
                                       __HIP_MEMORY_SCOPE_AGENT);
            } while ((unsigned)(pk >> 32) != tag);
            h_lds[rc + 4 * (rc >> 6)] = __uint_as_float((unsigned)pk);
        } else if (tid >= 320) {
            // stage x_{t(s+1)}; prefetch x_{t(s+2)}
            const int i0 = tid - 320;
            x_lds[i0 + 4 * (i0 >> 5)] = xr0;
            { const int c1 = i0 + 64; x_lds[c1 + 4 * (c1 >> 5)] = xr1; }
            int tn = dir ? (NT - 3 - s) : (s + 2);
            tn = tn < 0 ? 0 : (tn >= NT ? NT - 1 : tn);
            xr0 = xb[(size_t)tn * NI + i0];
            xr1 = xb[(size_t)tn * NI + i0 + 64];
        }
        __syncthreads();

        // ---- Phase B: dots for step s+1 -> g[pw] ----
        if (s < NT - 1) {
            float ah0 = 0.f, ah1 = 0.f, ah2 = 0.f, ah3 = 0.f;
            float ax0 = 0.f, ax1 = 0.f;
            const float* hp = h_lds + q * 68;
            #pragma unroll
            for (int i = 0; i < 16; ++i) {
                ah0 += wh[i]      * hp[i];
                ah1 += wh[16 + i] * hp[16 + i];
                ah2 += wh[32 + i] * hp[32 + i];
                ah3 += wh[48 + i] * hp[48 + i];
            }
            const float* xp = x_lds + q * 36;
            #pragma unroll
            for (int i = 0; i < 16; ++i) {
                ax0 += wi[i]      * xp[i];
                ax1 += wi[16 + i] * xp[16 + i];
            }
            float ah = (ah0 + ah1) + (ah2 + ah3);
            float ax = ax0 + ax1;
            ah += __shfl_xor(ah, 1); ah += __shfl_xor(ah, 2);
            ax += __shfl_xor(ax, 1); ax += __shfl_xor(ax, 2);
            if (q == 0) { gx_l[pw][row] = ax + bi; gh_l[pw][row] = ah + bh; }
            __syncthreads();
        }
    }
}

// ---------------------------------------------------------------------------
// w_att transpose: wT[k][h] = w_att[h][k]
// ---------------------------------------------------------------------------
__global__ void transpose_watt(const float* __restrict__ w_att, float* __restrict__ wT) {
    const int n = blockIdx.x * 256 + threadIdx.x;   // 0..262143
    const int k = n >> 9, h = n & 511;
    wT[n] = w_att[h * NH2 + k];
}

// ---------------------------------------------------------------------------
// Fused scores = sum_k tanh(pred @ w_att)[.,k] * v[k], tiled 64t x 64k,
// K(=h)=512 chunked by 64 through LDS. Partial scores via atomicAdd.
// ---------------------------------------------------------------------------
__global__ __launch_bounds__(256) void scores_gemm(
    const float* __restrict__ pred, const float* __restrict__ wT,
    const float* __restrict__ v_att, float* __restrict__ scores)
{
    const int tt = blockIdx.x, kt = blockIdx.y, bb = blockIdx.z;
    const int tid = threadIdx.x;
    const int tx = tid & 15;   // k micro index
    const int ty = tid >> 4;   // t micro index
    __shared__ float As[64][68];   // [t][h]
    __shared__ float Bs[64][68];   // [h][k]
    __shared__ float red[64][17];
    float acc[4][4] = {{0.f}};
    const int t0 = tt * 64, k0 = kt * 64;
    const float* pb = pred + ((size_t)bb * NT + t0) * NH2;

    for (int hc = 0; hc < NH2; hc += 64) {
        #pragma unroll
        for (int r = 0; r < 4; ++r) {
            const int idx = tid + 256 * r;
            const int tr = idx >> 4;           // row 0..63
            const int c4 = (idx & 15) * 4;     // col 0..60
            float4 a = *(const float4*)(pb + (size_t)tr * NH2 + hc + c4);
            *(float4*)&As[tr][c4] = a;
            float4 w = *(const float4*)(wT + (size_t)(k0 + tr) * NH2 + hc + c4);
            Bs[c4 + 0][tr] = w.x; Bs[c4 + 1][tr] = w.y;
            Bs[c4 + 2][tr] = w.z; Bs[c4 + 3][tr] = w.w;
        }
        __syncthreads();
        #pragma unroll
        for (int h = 0; h < 64; ++h) {
            const float a0 = As[ty*4+0][h], a1 = As[ty*4+1][h];
            const float a2 = As[ty*4+2][h], a3 = As[ty*4+3][h];
            const float4 bv = *(const float4*)&Bs[h][tx*4];
            acc[0][0] += a0*bv.x; acc[0][1] += a0*bv.y; acc[0][2] += a0*bv.z; acc[0][3] += a0*bv.w;
            acc[1][0] += a1*bv.x; acc[1][1] += a1*bv.y; acc[1][2] += a1*bv.z; acc[1][3] += a1*bv.w;
            acc[2][0] += a2*bv.x; acc[2][1] += a2*bv.y; acc[2][2] += a2*bv.z; acc[2][3] += a2*bv.w;
            acc[3][0] += a3*bv.x; acc[3][1] += a3*bv.y; acc[3][2] += a3*bv.z; acc[3][3] += a3*bv.w;
        }
        __syncthreads();
    }
    const float4 vv = *(const float4*)(v_att + k0 + tx * 4);
    #pragma unroll
    for (int i = 0; i < 4; ++i) {
        const float p = tanhf(acc[i][0]) * vv.x + tanhf(acc[i][1]) * vv.y
                      + tanhf(acc[i][2]) * vv.z + tanhf(acc[i][3]) * vv.w;
        red[ty*4+i][tx] = p;
    }
    __syncthreads();
    if (tid < 64) {
        float ssum = 0.f;
        #pragma unroll
        for (int xx = 0; xx < 16; ++xx) ssum += red[tid][xx];
        atomicAdd(&scores[bb * NT + t0 + tid], ssum);
    }
}

// ---------------------------------------------------------------------------
// softmax over T per batch (in-place)
// ---------------------------------------------------------------------------
__global__ void softmax_t(float* __restrict__ scores) {
    const int bb = blockIdx.x;
    const int tid = threadIdx.x;   // 256
    __shared__ float red[256];
    float m = -1e30f;
    for (int t = tid; t < NT; t += 256) m = fmaxf(m, scores[bb*NT + t]);
    red[tid] = m; __syncthreads();
    for (int s2 = 128; s2; s2 >>= 1) { if (tid < s2) red[tid] = fmaxf(red[tid], red[tid+s2]); __syncthreads(); }
    m = red[0]; __syncthreads();
    float sum = 0.f;
    for (int t = tid; t < NT; t += 256) sum += expf(scores[bb*NT + t] - m);
    red[tid] = sum; __syncthreads();
    for (int s2 = 128; s2; s2 >>= 1) { if (tid < s2) red[tid] += red[tid+s2]; __syncthreads(); }
    const float inv = 1.f / red[0];
    for (int t = tid; t < NT; t += 256) scores[bb*NT + t] = expf(scores[bb*NT + t] - m) * inv;
}

// ---------------------------------------------------------------------------
// ctx[b][h] = sum_t a[b][t] * pred[b][t][h]  (partial per t-chunk, atomicAdd)
// ---------------------------------------------------------------------------
__global__ void ctx_kernel(const float* __restrict__ pred, const float* __restrict__ a,
                           float* __restrict__ ctx) {
    const int bb = blockIdx.x, ch = blockIdx.y;   // 32 chunks of 128 t
    const int tid = threadIdx.x;                  // 256
    const int t0 = ch * 128;
    float acc0 = 0.f, acc1 = 0.f;
    for (int t = 0; t < 128; ++t) {
        const float av = a[bb*NT + t0 + t];
        const float* p = pred + ((size_t)bb * NT + t0 + t) * NH2;
        acc0 += av * p[tid];
        acc1 += av * p[tid + 256];
    }
    atomicAdd(&ctx[bb*NH2 + tid], acc0);
    atomicAdd(&ctx[bb*NH2 + tid + 256], acc1);
}

// ---------------------------------------------------------------------------
// logits = ctx @ w_lin^T + b_lin ; out = softmax(logits) per batch.
// ---------------------------------------------------------------------------
__global__ __launch_bounds__(512) void final_kernel(
    const float* __restrict__ ctx, const float* __restrict__ w_lin,
    const float* __restrict__ b_lin, float* __restrict__ out)
{
    const int tid = threadIdx.x;
    const int bb = tid >> 6, o = tid & 63;
    __shared__ float cl[NB][NH2];
    for (int i = tid; i < NB * NH2; i += 512) cl[i >> 9][i & 511] = ctx[i];
    __syncthreads();
    float acc = b_lin[o];
    for (int h = 0; h < NH2; h += 4) {
        const float4 w = *(const float4*)&w_lin[o * NH2 + h];
        acc += cl[bb][h]*w.x + cl[bb][h+1]*w.y + cl[bb][h+2]*w.z + cl[bb][h+3]*w.w;
    }
    float m = acc;
    for (int off = 32; off; off >>= 1) m = fmaxf(m, __shfl_xor(m, off));
    const float e = expf(acc - m);
    float ssum = e;
    for (int off = 32; off; off >>= 1) ssum += __shfl_xor(ssum, off);
    out[tid] = e / ssum;
}

extern "C" void kernel_launch(void* const* d_in, const int* in_sizes, int n_in,
                              void* d_out, int out_size, void* d_ws, size_t ws_size,
                              hipStream_t stream) {
    (void)in_sizes; (void)n_in; (void)out_size; (void)ws_size;
    const float* x      = (const float*)d_in[0];
    const float* w_ih_f = (const float*)d_in[1];
    const float* w_hh_f = (const float*)d_in[2];
    const float* b_ih_f = (const float*)d_in[3];
    const float* b_hh_f = (const float*)d_in[4];
    const float* w_ih_b = (const float*)d_in[5];
    const float* w_hh_b = (const float*)d_in[6];
    const float* b_ih_b = (const float*)d_in[7];
    const float* b_hh_b = (const float*)d_in[8];
    const float* w_att  = (const float*)d_in[9];
    const float* v_att  = (const float*)d_in[10];
    const float* w_lin  = (const float*)d_in[11];
    const float* b_lin  = (const float*)d_in[12];

    float* ws     = (float*)d_ws;
    unsigned long long* mir = (unsigned long long*)(ws + OFF_MIR);
    float* scores = ws + OFF_SC;     // softmax in-place -> also 'a'
    float* ctx    = ws + OFF_CTX;
    float* wT     = ws + OFF_WT;
    float* pred   = ws + OFF_PRED;
    float* out    = (float*)d_out;

    hipMemsetAsync(d_ws, 0, (size_t)ZERO_FLOATS * sizeof(float), stream);
    hipLaunchKernelGGL(transpose_watt, dim3(1024), dim3(256), 0, stream, w_att, wT);
    hipLaunchKernelGGL(gru_rec, dim3(128), dim3(384), 0, stream,
                       x, w_ih_f, w_hh_f, b_ih_f, b_hh_f,
                       w_ih_b, w_hh_b, b_ih_b, b_hh_b, mir, pred);
    hipLaunchKernelGGL(scores_gemm, dim3(64, 8, 8), dim3(256), 0, stream,
                       pred, wT, v_att, scores);
    hipLaunchKernelGGL(softmax_t, dim3(8), dim3(256), 0, stream, scores);
    hipLaunchKernelGGL(ctx_kernel, dim3(8, 32), dim3(256), 0, stream, pred, scores, ctx);
    hipLaunchKernelGGL(final_kernel, dim3(1), dim3(512), 0, stream, ctx, w_lin, b_lin, out);
}